// Round 1
// baseline (401.753 us; speedup 1.0000x reference)
//
#include <hip/hip_runtime.h>
#include <hip/hip_fp16.h>
#include <stdint.h>

// LRU single-step collapsed:  y = u @ M^T + y0
//   M  = 2*(C_re G B_re - C_im G B_im) + D     (G = diag(exp(gamma_log)))  [1024x1024]
//   y0 = 2*(C_re c_re - C_im c_im),  c = lambda * x  (x not batched)
// GEMMs run as f16 MFMA with 3-product hi/lo split (fp32-grade accuracy).

typedef _Float16 f16x8 __attribute__((ext_vector_type(8)));
typedef float f32x4 __attribute__((ext_vector_type(4)));

#define GLOBAL_AS __attribute__((address_space(1)))
#define LDS_AS __attribute__((address_space(3)))

constexpr int BATCH = 16384, DIN = 1024, DSTATE = 2048, DOUT = 1024;
constexpr int S2 = 2 * DSTATE;  // 4096
constexpr int BK = 32;          // K elems per tile step (one 16x16x32 MFMA k-step)

// Tile rows are 32 f16 = 64B = 4 x 16B slots. XOR-swizzle slot by ((row>>1)&3):
// 16 lanes reading the same slot-column across rows 0..15 spread over all 32 banks
// (2-way aliasing = free per m136).
__device__ __forceinline__ int lds_off(int row, int k) {
  int slot = k >> 3;
  int sl = slot ^ ((row >> 1) & 3);
  return row * 64 + sl * 16 + (k & 7) * 2;
}

// ---------------- per-state constants ----------------
__global__ void k_state(const float* __restrict__ xr, const float* __restrict__ xi,
                        const float* __restrict__ nu, const float* __restrict__ th,
                        const float* __restrict__ ga, float* __restrict__ g,
                        float* __restrict__ cre, float* __restrict__ cim) {
  int s = blockIdx.x * 256 + threadIdx.x;
  if (s < DSTATE) {
    float lm = expf(-expf(nu[s]));
    float t = expf(th[s]);
    float lr = lm * cosf(t), li = lm * sinf(t);
    g[s] = expf(ga[s]);
    cre[s] = lr * xr[s] - li * xi[s];
    cim[s] = lr * xi[s] + li * xr[s];
  }
}

// ---------------- y0[j] = 2*(sum_s cre*C_re[j,s] - cim*C_im[j,s]) ----------------
__global__ void k_y0(const float* __restrict__ cre, const float* __restrict__ cim,
                     const float* __restrict__ Cre, const float* __restrict__ Cim,
                     float* __restrict__ y0) {
  int j = blockIdx.x;
  float acc = 0.f;
  for (int s = threadIdx.x; s < DSTATE; s += 256)
    acc += cre[s] * Cre[(long)j * DSTATE + s] - cim[s] * Cim[(long)j * DSTATE + s];
  for (int off = 32; off; off >>= 1) acc += __shfl_down(acc, off);
  __shared__ float red[4];
  if ((threadIdx.x & 63) == 0) red[threadIdx.x >> 6] = acc;
  __syncthreads();
  if (threadIdx.x == 0) y0[j] = 2.f * (red[0] + red[1] + red[2] + red[3]);
}

// ---------------- Bgt[i][s2] = gamma[s]*B[s][i], transposed, f16 hi/lo split ----------------
__global__ void k_bgt(const float* __restrict__ Bre, const float* __restrict__ Bim,
                      const float* __restrict__ g, __half* __restrict__ Bh,
                      __half* __restrict__ Bl) {
  __shared__ float tile[32][33];
  int s0 = blockIdx.x * 32, i0 = blockIdx.y * 32;
  int c = threadIdx.x & 31, r0 = threadIdx.x >> 5;  // 8 rows per pass
  const float* src = (s0 < DSTATE) ? Bre : Bim;
  int sbase = (s0 < DSTATE) ? s0 : s0 - DSTATE;
  for (int rr = 0; rr < 32; rr += 8) {
    int s = sbase + r0 + rr;
    tile[r0 + rr][c] = src[(long)s * DIN + i0 + c] * g[s];
  }
  __syncthreads();
  for (int rr = 0; rr < 32; rr += 8) {
    int i = i0 + r0 + rr;
    float v = tile[c][r0 + rr];
    __half h = __float2half(v);
    __half l = __float2half(v - __half2float(h));
    Bh[(long)i * S2 + s0 + c] = h;
    Bl[(long)i * S2 + s0 + c] = l;
  }
}

// ---------------- GEMM: out[M][N] = A[M][K] @ B^T[N][K] (+epilogue) ----------------
// A is fp32, split on the fly into hi/lo f16 tiles (reg-staged, swizzled ds_write).
// B pre-split f16 hi/lo, staged via global_load_lds with inverse-swizzled source.
// 3-product MFMA: ah*bh + ah*bl + al*bh.
// ASRC==1: A is the virtual concat [2*C_re | -2*C_im] (A=Cre, A2=Cim, stride DSTATE).
// EPI==0:  M-build: += D, write f16 hi/lo.   EPI==1: y: += y0[col], write fp32.
template <int BM, int BN, int EPI, int ASRC>
__global__ __launch_bounds__(256, 2) void k_gemm(
    const float* __restrict__ A, const float* __restrict__ A2,
    const __half* __restrict__ Bh, const __half* __restrict__ Bl,
    const float* __restrict__ extra, float* __restrict__ outF,
    __half* __restrict__ outH, __half* __restrict__ outL, int M, int N, int K) {
  constexpr int FM = BM / 32;  // 16x16 frags per wave (wave tile = BM/2 x BN/2)
  constexpr int FN = BN / 32;
  constexpr int ABYTES = BM * 64;
  constexpr int BBYTES = BN * 64;
  __shared__ alignas(16) char smem[2 * ABYTES + 2 * BBYTES];
  char* sAh = smem;
  char* sAl = smem + ABYTES;
  char* sBh = smem + 2 * ABYTES;
  char* sBl = smem + 2 * ABYTES + BBYTES;

  const int tid = threadIdx.x;
  const int lane = tid & 63;
  const int wid = tid >> 6;
  const int wr = wid >> 1, wc = wid & 1;  // 2x2 wave grid
  const int bm0 = blockIdx.y * BM;
  const int bn0 = blockIdx.x * BN;
  const int r16 = lane & 15;
  const int ksl = lane >> 4;

  f32x4 acc[FM][FN];
#pragma unroll
  for (int i = 0; i < FM; ++i)
#pragma unroll
    for (int j = 0; j < FN; ++j) acc[i][j] = f32x4{0.f, 0.f, 0.f, 0.f};

  constexpr int APT = (BM * 8) / 256;  // float4 loads per thread for A tile
  constexpr int IPW = (BN / 16) / 4;   // global_load_lds insts per wave per tile

  for (int kt = 0; kt < K / BK; ++kt) {
    __syncthreads();
    // ---- stage A: fp32 -> (hi,lo) f16, swizzled ds_write ----
#pragma unroll
    for (int it = 0; it < APT; ++it) {
      int idx = it * 256 + tid;
      int row = idx >> 3;        // 8 float4 per 32-elem row
      int k0 = (idx & 7) * 4;
      f32x4 v;
      if (ASRC == 0) {
        v = *(const f32x4*)(A + (long)(bm0 + row) * K + kt * BK + k0);
      } else {
        int s = kt * BK + k0;  // kt*32 block never straddles DSTATE
        const float* src = (s < DSTATE) ? A : A2;
        int sc = (s < DSTATE) ? s : s - DSTATE;
        v = *(const f32x4*)(src + (long)(bm0 + row) * DSTATE + sc);
        v *= (s < DSTATE) ? 2.f : -2.f;
      }
      union { __half h[4]; uint64_t u; } ph, pl;
#pragma unroll
      for (int j = 0; j < 4; ++j) {
        float f = v[j];
        __half hh = __float2half(f);
        ph.h[j] = hh;
        pl.h[j] = __float2half(f - __half2float(hh));
      }
      int off = lds_off(row, k0);
      *(uint64_t*)(sAh + off) = ph.u;
      *(uint64_t*)(sAl + off) = pl.u;
    }
    // ---- stage B: global_load_lds, source pre-swizzled (linear LDS dest) ----
#pragma unroll
    for (int ii = 0; ii < IPW; ++ii) {
      int inst = wid * IPW + ii;
      int row = inst * 16 + (lane >> 2);
      int slot = (lane & 3) ^ ((row >> 1) & 3);  // inverse of read swizzle
      const __half* gh = Bh + (long)(bn0 + row) * K + kt * BK + slot * 8;
      const __half* gl = Bl + (long)(bn0 + row) * K + kt * BK + slot * 8;
      __builtin_amdgcn_global_load_lds((GLOBAL_AS const unsigned int*)gh,
                                       (LDS_AS unsigned int*)(sBh + inst * 1024), 16, 0, 0);
      __builtin_amdgcn_global_load_lds((GLOBAL_AS const unsigned int*)gl,
                                       (LDS_AS unsigned int*)(sBl + inst * 1024), 16, 0, 0);
    }
    __syncthreads();
    // ---- compute: 3-product split ----
    f16x8 ah[FM], al[FM], bh[FN], bl[FN];
#pragma unroll
    for (int m = 0; m < FM; ++m) {
      int row = wr * (BM / 2) + m * 16 + r16;
      ah[m] = *(const f16x8*)(sAh + lds_off(row, ksl * 8));
      al[m] = *(const f16x8*)(sAl + lds_off(row, ksl * 8));
    }
#pragma unroll
    for (int n = 0; n < FN; ++n) {
      int row = wc * (BN / 2) + n * 16 + r16;
      bh[n] = *(const f16x8*)(sBh + lds_off(row, ksl * 8));
      bl[n] = *(const f16x8*)(sBl + lds_off(row, ksl * 8));
    }
#pragma unroll
    for (int m = 0; m < FM; ++m)
#pragma unroll
      for (int n = 0; n < FN; ++n)
        acc[m][n] = __builtin_amdgcn_mfma_f32_16x16x32_f16(ah[m], bh[n], acc[m][n], 0, 0, 0);
#pragma unroll
    for (int m = 0; m < FM; ++m)
#pragma unroll
      for (int n = 0; n < FN; ++n)
        acc[m][n] = __builtin_amdgcn_mfma_f32_16x16x32_f16(ah[m], bl[n], acc[m][n], 0, 0, 0);
#pragma unroll
    for (int m = 0; m < FM; ++m)
#pragma unroll
      for (int n = 0; n < FN; ++n)
        acc[m][n] = __builtin_amdgcn_mfma_f32_16x16x32_f16(al[m], bh[n], acc[m][n], 0, 0, 0);
  }

  // ---- epilogue (C/D layout: col = lane&15, row = (lane>>4)*4 + reg) ----
  const int rowb = (lane >> 4) * 4;
#pragma unroll
  for (int m = 0; m < FM; ++m)
#pragma unroll
    for (int n = 0; n < FN; ++n)
#pragma unroll
      for (int r = 0; r < 4; ++r) {
        int gr = bm0 + wr * (BM / 2) + m * 16 + rowb + r;
        int gc = bn0 + wc * (BN / 2) + n * 16 + r16;
        float v = acc[m][n][r];
        if constexpr (EPI == 0) {
          float mv = v + extra[(long)gr * N + gc];  // + D[j][i]
          __half h = __float2half(mv);
          __half l = __float2half(mv - __half2float(h));
          outH[(long)gr * N + gc] = h;
          outL[(long)gr * N + gc] = l;
        } else {
          outF[(long)gr * N + gc] = v + extra[gc];  // + y0[j]
        }
      }
}

extern "C" void kernel_launch(void* const* d_in, const int* in_sizes, int n_in,
                              void* d_out, int out_size, void* d_ws, size_t ws_size,
                              hipStream_t stream) {
  const float* u   = (const float*)d_in[0];
  const float* xr  = (const float*)d_in[1];
  const float* xi  = (const float*)d_in[2];
  const float* nu  = (const float*)d_in[3];
  const float* th  = (const float*)d_in[4];
  const float* ga  = (const float*)d_in[5];
  const float* Bre = (const float*)d_in[6];
  const float* Bim = (const float*)d_in[7];
  const float* Cre = (const float*)d_in[8];
  const float* Cim = (const float*)d_in[9];
  const float* Dm  = (const float*)d_in[10];
  float* y = (float*)d_out;

  char* w = (char*)d_ws;
  float* g   = (float*)(w);              // 2048 f32
  float* cre = (float*)(w + 8192);       // 2048
  float* cim = (float*)(w + 16384);      // 2048
  float* y0  = (float*)(w + 24576);      // 1024
  __half* Bgh = (__half*)(w + 32768);                       // [DIN][S2] 8 MB
  __half* Bgl = (__half*)(w + 32768 + 8388608);             // 8 MB
  __half* Mh  = (__half*)(w + 32768 + 2 * 8388608);         // [DOUT][DIN] 2 MB
  __half* Ml  = (__half*)(w + 32768 + 2 * 8388608 + 2097152);
  // total ws use ~20.1 MB

  k_state<<<DSTATE / 256, 256, 0, stream>>>(xr, xi, nu, th, ga, g, cre, cim);
  k_y0<<<DOUT, 256, 0, stream>>>(cre, cim, Cre, Cim, y0);
  k_bgt<<<dim3(S2 / 32, DIN / 32), 256, 0, stream>>>(Bre, Bim, g, Bgh, Bgl);
  // M-build: M[j][i] = sum_s [2Cre|-2Cim][j][s] * Bgt[i][s]  (+D), K=4096
  k_gemm<64, 64, 0, 1><<<dim3(DIN / 64, DOUT / 64), 256, 0, stream>>>(
      Cre, Cim, Bgh, Bgl, Dm, nullptr, Mh, Ml, DOUT, DIN, S2);
  // main: y[b][j] = sum_i u[b][i] * M[j][i] + y0[j], K=1024
  k_gemm<128, 128, 1, 0><<<dim3(DOUT / 128, BATCH / 128), 256, 0, stream>>>(
      u, nullptr, Mh, Ml, y0, y, nullptr, nullptr, BATCH, DOUT, DIN);
}

// Round 3
// 280.513 us; speedup vs baseline: 1.4322x; 1.4322x over previous
//
#include <hip/hip_runtime.h>
#include <hip/hip_fp16.h>
#include <stdint.h>

// LRU single-step collapsed:  y = u @ M^T + y0
//   M  = 2*(C_re G B_re - C_im G B_im) + D     (G = diag(exp(gamma_log)))  [1024x1024]
//   y0 = 2*(C_re c_re - C_im c_im),  c = lambda * x
// f16 MFMA with scaled hi/lo split (x256 so lo-parts are f16-normal, no denormal flush).
// M-build: 3-product split-K GEMM -> fp32 partials -> reduce(+D, resplit x256).
// Main GEMM: 2-product (u_hi * (Mh + Ml)), epilogue /256 + y0.

typedef _Float16 f16x8 __attribute__((ext_vector_type(8)));
typedef __fp16 fp16x2 __attribute__((ext_vector_type(2)));
typedef float f32x4 __attribute__((ext_vector_type(4)));

#define GLOBAL_AS __attribute__((address_space(1)))
#define LDS_AS __attribute__((address_space(3)))

constexpr int BATCH = 16384, DIN = 1024, DSTATE = 2048, DOUT = 1024;
constexpr int S2 = 2 * DSTATE;  // 4096
constexpr int KSPLIT = 4;       // M-build split-K chunks

// Rows are 32 f16 = 64B = 4 x 16B slots; XOR-swizzle slot by ((row>>1)&3).
// Verified: SQ_LDS_BANK_CONFLICT == 0 in round 1.
__device__ __forceinline__ int lds_off(int row, int k) {
  int slot = k >> 3;
  int sl = slot ^ ((row >> 1) & 3);
  return row * 64 + sl * 16 + (k & 7) * 2;
}

// ---------------- per-state constants ----------------
__global__ void k_state(const float* __restrict__ xr, const float* __restrict__ xi,
                        const float* __restrict__ nu, const float* __restrict__ th,
                        const float* __restrict__ ga, float* __restrict__ g,
                        float* __restrict__ cre, float* __restrict__ cim) {
  int s = blockIdx.x * 256 + threadIdx.x;
  if (s < DSTATE) {
    float lm = expf(-expf(nu[s]));
    float t = expf(th[s]);
    float lr = lm * cosf(t), li = lm * sinf(t);
    g[s] = expf(ga[s]);
    cre[s] = lr * xr[s] - li * xi[s];
    cim[s] = lr * xi[s] + li * xr[s];
  }
}

// ---------------- y0[j] = 2*(sum_s cre*C_re[j,s] - cim*C_im[j,s]) ----------------
__global__ void k_y0(const float* __restrict__ cre, const float* __restrict__ cim,
                     const float* __restrict__ Cre, const float* __restrict__ Cim,
                     float* __restrict__ y0) {
  int j = blockIdx.x;
  float acc = 0.f;
  for (int s = threadIdx.x; s < DSTATE; s += 256)
    acc += cre[s] * Cre[(long)j * DSTATE + s] - cim[s] * Cim[(long)j * DSTATE + s];
  for (int off = 32; off; off >>= 1) acc += __shfl_down(acc, off);
  __shared__ float red[4];
  if ((threadIdx.x & 63) == 0) red[threadIdx.x >> 6] = acc;
  __syncthreads();
  if (threadIdx.x == 0) y0[j] = 2.f * (red[0] + red[1] + red[2] + red[3]);
}

// ---------------- Bgt[i][s2] = 256*gamma[s]*B[s][i], transposed, f16 hi/lo ----------------
__global__ void k_bgt(const float* __restrict__ Bre, const float* __restrict__ Bim,
                      const float* __restrict__ g, __half* __restrict__ Bh,
                      __half* __restrict__ Bl) {
  __shared__ float tile[32][33];
  int s0 = blockIdx.x * 32, i0 = blockIdx.y * 32;
  int c = threadIdx.x & 31, r0 = threadIdx.x >> 5;  // 8 rows per pass
  const float* src = (s0 < DSTATE) ? Bre : Bim;
  int sbase = (s0 < DSTATE) ? s0 : s0 - DSTATE;
  for (int rr = 0; rr < 32; rr += 8) {
    int s = sbase + r0 + rr;
    tile[r0 + rr][c] = src[(long)s * DIN + i0 + c] * (256.f * g[s]);
  }
  __syncthreads();
  for (int rr = 0; rr < 32; rr += 8) {
    int i = i0 + r0 + rr;
    float v = tile[c][r0 + rr];
    __half h = __float2half(v);
    __half l = __float2half(v - __half2float(h));
    Bh[(long)i * S2 + s0 + c] = h;
    Bl[(long)i * S2 + s0 + c] = l;
  }
}

// ---------------- GEMM: out[M][N](+partial) = A[M][K] @ B^T[N][K] ----------------
// EPI==0: M-build chunk (3-product, A = 512*[Cre|-Cim] split hi/lo on the fly,
//         fp32 partial written at outF + z*M*N).
// EPI==1: main (2-product, A = u rounded to f16 via pkrtz; y = acc/256 + y0[col]).
template <int BM, int BN, int EPI, int ASRC>
__global__ __launch_bounds__(256, 2) void k_gemm(
    const float* __restrict__ A, const float* __restrict__ A2,
    const __half* __restrict__ Bh, const __half* __restrict__ Bl,
    const float* __restrict__ extra, float* __restrict__ outF,
    int M, int N, int K, int kiters) {
  constexpr int FM = BM / 32;
  constexpr int FN = BN / 32;
  constexpr int ASPL = (EPI == 0) ? 2 : 1;  // hi(+lo) A buffers
  constexpr int ABYTES = BM * 64;
  constexpr int BBYTES = BN * 64;
  __shared__ alignas(16) char smem[ASPL * ABYTES + 2 * BBYTES];
  char* sAh = smem;
  char* sAl = smem + ABYTES;  // only used when ASPL==2
  char* sBh = smem + ASPL * ABYTES;
  char* sBl = smem + ASPL * ABYTES + BBYTES;

  const int tid = threadIdx.x;
  const int lane = tid & 63;
  const int wid = tid >> 6;
  const int wr = wid >> 1, wc = wid & 1;
  int bm0, bn0, kb;
  if constexpr (EPI == 1) {
    // XCD-aware swizzle: 1D grid of 1024; XCD k owns by in [k*16, k*16+16).
    int wg = blockIdx.x;
    int lin = (wg & 7) * 128 + (wg >> 3);
    bm0 = (lin >> 3) * BM;
    bn0 = (lin & 7) * BN;
    kb = 0;
  } else {
    bm0 = blockIdx.y * BM;
    bn0 = blockIdx.x * BN;
    kb = blockIdx.z * (S2 / KSPLIT);
  }
  const int r16 = lane & 15;
  const int ksl = lane >> 4;

  f32x4 acc[FM][FN];
#pragma unroll
  for (int i = 0; i < FM; ++i)
#pragma unroll
    for (int j = 0; j < FN; ++j) acc[i][j] = f32x4{0.f, 0.f, 0.f, 0.f};

  constexpr int APT = (BM * 8) / 256;  // f32x4 loads per thread for A tile
  constexpr int IPW = (BN / 16) / 4;   // global_load_lds insts per wave per buffer

  for (int kt = 0; kt < kiters; ++kt) {
    __syncthreads();
    // ---- stage A ----
#pragma unroll
    for (int it = 0; it < APT; ++it) {
      int idx = it * 256 + tid;
      int row = idx >> 3;
      int k0 = (idx & 7) * 4;
      f32x4 v;
      if (ASRC == 0) {
        v = *(const f32x4*)(A + (long)(bm0 + row) * K + kb + kt * 32 + k0);
      } else {
        int s = kb + kt * 32 + k0;  // chunk never straddles DSTATE
        const float* src = (s < DSTATE) ? A : A2;
        int sc = (s < DSTATE) ? s : s - DSTATE;
        v = *(const f32x4*)(src + (long)(bm0 + row) * DSTATE + sc);
        v *= (s < DSTATE) ? 512.f : -512.f;  // 2*scale(256)
      }
      int off = lds_off(row, k0);
      if constexpr (EPI == 1) {
        union { uint32_t w[2]; uint64_t u; } p;
        fp16x2 h0 = __builtin_amdgcn_cvt_pkrtz(v[0], v[1]);
        fp16x2 h1 = __builtin_amdgcn_cvt_pkrtz(v[2], v[3]);
        p.w[0] = __builtin_bit_cast(uint32_t, h0);
        p.w[1] = __builtin_bit_cast(uint32_t, h1);
        *(uint64_t*)(sAh + off) = p.u;
      } else {
        union { __half h[4]; uint64_t u; } ph, pl;
#pragma unroll
        for (int j = 0; j < 4; ++j) {
          __half hh = __float2half(v[j]);
          ph.h[j] = hh;
          pl.h[j] = __float2half(v[j] - __half2float(hh));
        }
        *(uint64_t*)(sAh + off) = ph.u;
        *(uint64_t*)(sAl + off) = pl.u;
      }
    }
    // ---- stage B via global_load_lds (linear dest, inverse-swizzled source) ----
#pragma unroll
    for (int ii = 0; ii < IPW; ++ii) {
      int inst = wid * IPW + ii;
      int row = inst * 16 + (lane >> 2);
      int slot = (lane & 3) ^ ((row >> 1) & 3);
      const __half* gh = Bh + (long)(bn0 + row) * K + kb + kt * 32 + slot * 8;
      const __half* gl = Bl + (long)(bn0 + row) * K + kb + kt * 32 + slot * 8;
      __builtin_amdgcn_global_load_lds((GLOBAL_AS const unsigned int*)gh,
                                       (LDS_AS unsigned int*)(sBh + inst * 1024), 16, 0, 0);
      __builtin_amdgcn_global_load_lds((GLOBAL_AS const unsigned int*)gl,
                                       (LDS_AS unsigned int*)(sBl + inst * 1024), 16, 0, 0);
    }
    __syncthreads();
    // ---- compute ----
    f16x8 ah[FM], bh[FN], bl[FN];
    f16x8 al[FM];
#pragma unroll
    for (int m = 0; m < FM; ++m) {
      int row = wr * (BM / 2) + m * 16 + r16;
      ah[m] = *(const f16x8*)(sAh + lds_off(row, ksl * 8));
      if constexpr (EPI == 0) al[m] = *(const f16x8*)(sAl + lds_off(row, ksl * 8));
    }
#pragma unroll
    for (int n = 0; n < FN; ++n) {
      int row = wc * (BN / 2) + n * 16 + r16;
      bh[n] = *(const f16x8*)(sBh + lds_off(row, ksl * 8));
      bl[n] = *(const f16x8*)(sBl + lds_off(row, ksl * 8));
    }
#pragma unroll
    for (int m = 0; m < FM; ++m)
#pragma unroll
      for (int n = 0; n < FN; ++n)
        acc[m][n] = __builtin_amdgcn_mfma_f32_16x16x32_f16(ah[m], bh[n], acc[m][n], 0, 0, 0);
#pragma unroll
    for (int m = 0; m < FM; ++m)
#pragma unroll
      for (int n = 0; n < FN; ++n)
        acc[m][n] = __builtin_amdgcn_mfma_f32_16x16x32_f16(ah[m], bl[n], acc[m][n], 0, 0, 0);
    if constexpr (EPI == 0) {
#pragma unroll
      for (int m = 0; m < FM; ++m)
#pragma unroll
        for (int n = 0; n < FN; ++n)
          acc[m][n] = __builtin_amdgcn_mfma_f32_16x16x32_f16(al[m], bh[n], acc[m][n], 0, 0, 0);
    }
  }

  // ---- epilogue (C/D layout: col = lane&15, row = (lane>>4)*4 + reg) ----
  const int rowb = (lane >> 4) * 4;
#pragma unroll
  for (int m = 0; m < FM; ++m)
#pragma unroll
    for (int n = 0; n < FN; ++n)
#pragma unroll
      for (int r = 0; r < 4; ++r) {
        int gr = bm0 + wr * (BM / 2) + m * 16 + rowb + r;
        int gc = bn0 + wc * (BN / 2) + n * 16 + r16;
        if constexpr (EPI == 0) {
          outF[(long)blockIdx.z * M * N + (long)gr * N + gc] = acc[m][n][r];
        } else {
          outF[(long)gr * N + gc] = acc[m][n][r] * (1.f / 256.f) + extra[gc];
        }
      }
}

// ---------------- reduce split-K partials: M = sum/65536 + D, store 256*M hi/lo ----
__global__ void k_redM(const float* __restrict__ P, const float* __restrict__ D,
                       __half* __restrict__ Mh, __half* __restrict__ Ml) {
  int idx = (blockIdx.x * 256 + threadIdx.x) * 4;
  f32x4 s = *(const f32x4*)(P + idx);
  s += *(const f32x4*)(P + (1 << 20) + idx);
  s += *(const f32x4*)(P + (2 << 20) + idx);
  s += *(const f32x4*)(P + (3 << 20) + idx);
  f32x4 d = *(const f32x4*)(D + idx);
  union { __half h[4]; uint64_t u; } ph, pl;
#pragma unroll
  for (int j = 0; j < 4; ++j) {
    float v = s[j] * (1.f / 256.f) + 256.f * d[j];  // = 256 * M[j]
    __half hh = __float2half(v);
    ph.h[j] = hh;
    pl.h[j] = __float2half(v - __half2float(hh));
  }
  *(uint64_t*)(Mh + idx) = ph.u;
  *(uint64_t*)(Ml + idx) = pl.u;
}

extern "C" void kernel_launch(void* const* d_in, const int* in_sizes, int n_in,
                              void* d_out, int out_size, void* d_ws, size_t ws_size,
                              hipStream_t stream) {
  const float* u   = (const float*)d_in[0];
  const float* xr  = (const float*)d_in[1];
  const float* xi  = (const float*)d_in[2];
  const float* nu  = (const float*)d_in[3];
  const float* th  = (const float*)d_in[4];
  const float* ga  = (const float*)d_in[5];
  const float* Bre = (const float*)d_in[6];
  const float* Bim = (const float*)d_in[7];
  const float* Cre = (const float*)d_in[8];
  const float* Cim = (const float*)d_in[9];
  const float* Dm  = (const float*)d_in[10];
  float* y = (float*)d_out;

  char* w = (char*)d_ws;
  float* g   = (float*)(w);
  float* cre = (float*)(w + 8192);
  float* cim = (float*)(w + 16384);
  float* y0  = (float*)(w + 24576);
  __half* Bgh = (__half*)(w + 32768);                        // [DIN][S2] 8 MB
  __half* Bgl = (__half*)(w + 32768 + 8388608);              // 8 MB
  __half* Mh  = (__half*)(w + 32768 + 2 * 8388608);          // 2 MB
  __half* Ml  = (__half*)(w + 32768 + 2 * 8388608 + 2097152);
  float* Mpart = (float*)(w + 32768 + 2 * 8388608 + 2 * 2097152);  // 16 MB
  // total ws use ~37.8 MB

  k_state<<<DSTATE / 256, 256, 0, stream>>>(xr, xi, nu, th, ga, g, cre, cim);
  k_y0<<<DOUT, 256, 0, stream>>>(cre, cim, Cre, Cim, y0);
  k_bgt<<<dim3(S2 / 32, DIN / 32), 256, 0, stream>>>(Bre, Bim, g, Bgh, Bgl);
  // M-build: split-K x4, fp32 partials
  k_gemm<64, 64, 0, 1><<<dim3(DIN / 64, DOUT / 64, KSPLIT), 256, 0, stream>>>(
      Cre, Cim, Bgh, Bgl, nullptr, Mpart, DOUT, DIN, S2, (S2 / KSPLIT) / 32);
  k_redM<<<1024, 256, 0, stream>>>(Mpart, Dm, Mh, Ml);
  // main: y[b][j] = (sum_i u_hi[b][i] * 256M[j][i])/256 + y0[j]
  k_gemm<128, 128, 1, 0><<<(BATCH / 128) * (DOUT / 128), 256, 0, stream>>>(
      u, nullptr, Mh, Ml, y0, y, BATCH, DOUT, DIN, DIN / 32);
}